// Round 7
// baseline (140.155 us; speedup 1.0000x reference)
//
#include <hip/hip_runtime.h>

// Problem constants: B,H,W,C = 16,256,256,16 ; HO,WO = 256,256
#define BB 16
#define HH 256
#define WW 256
#define CC 16
#define NPIX (HH * WW)            // 65536 pixels per batch
#define SLICES 128                // pool slices per batch
#define POOL_BLOCKS (BB * SLICES) // 2048 blocks
#define SAMPLE_BPB 128            // sample blocks per batch (2 rows each)
#define SAMPLE_BLOCKS (BB * SAMPLE_BPB)
#define MAXR 4                    // staged input rows budget (4 x 16 KB = 64 KB)

// ---------------------------------------------------------------------------
// Kernel 1: partial mean-pool. 2048 blocks, 256 threads. Deterministic.
// part[blk*4+g] (float4) = partial sums of channels 4g..4g+3, blk=b*128+s.
// ---------------------------------------------------------------------------
__global__ __launch_bounds__(256) void pool_partial(const float4* __restrict__ x4,
                                                    float4* __restrict__ part) {
    const int blk = blockIdx.x;
    const int tid = threadIdx.x;
    const float4* p = x4 + (size_t)blk * 2048 + tid;
    float4 acc = {0.f, 0.f, 0.f, 0.f};
#pragma unroll
    for (int k = 0; k < 8; ++k) {
        float4 v = p[k * 256];
        acc.x += v.x; acc.y += v.y; acc.z += v.z; acc.w += v.w;
    }
    for (int off = 4; off < 64; off <<= 1) {
        acc.x += __shfl_down(acc.x, off);
        acc.y += __shfl_down(acc.y, off);
        acc.z += __shfl_down(acc.z, off);
        acc.w += __shfl_down(acc.w, off);
    }
    __shared__ float4 wsum[4][4];
    const int wave = tid >> 6, lane = tid & 63;
    if (lane < 4) wsum[wave][lane] = acc;
    __syncthreads();
    if (tid < 4) {
        float4 t0 = wsum[0][tid], t1 = wsum[1][tid];
        float4 t2 = wsum[2][tid], t3 = wsum[3][tid];
        float4 t;
        t.x = t0.x + t1.x + t2.x + t3.x;
        t.y = t0.y + t1.y + t2.y + t3.y;
        t.z = t0.z + t1.z + t2.z + t3.z;
        t.w = t0.w + t1.w + t2.w + t3.w;
        part[blk * 4 + tid] = t;
    }
}

// ---------------------------------------------------------------------------
// Kernel 2: params prologue + LDS-staged bilinear sampling.
// Grid = 2048 blocks (b = blk>>7), 256 threads, 64 KB dynamic LDS
// (2 blocks/CU). Block covers 2 output rows (512 px); 4 lanes/pixel.
// The block's needed input-row band is computed from the tile corners of the
// (block-uniform) affine map; if it fits MAXR rows (typical: 3-4), rows are
// staged once into LDS and all corner reads are ds_read_b128 (conflict-free,
// lane addr ~ tid*16B). Fallback: direct global gather (always correct).
// ---------------------------------------------------------------------------
__global__ __launch_bounds__(256, 2) void sample_fused(
    const float4* __restrict__ x4,
    const float* __restrict__ W_loc,
    const float* __restrict__ b_loc,
    const float4* __restrict__ part,
    float4* __restrict__ out)
{
    extern __shared__ float lds_f[];              // 16384 floats = 64 KB
    float4* ldsRows = (float4*)lds_f;             // staged rows, 1024 f4/row
    float4* wsum    = (float4*)lds_f;             // prologue overlay [4][4]
    float*  pooled  = lds_f + 64;                 // [16]
    float*  prs     = lds_f + 80;                 // [6]

    const int tid  = threadIdx.x;
    const int blk  = blockIdx.x;                  // b*128 + local
    const int b    = blk >> 7;
    const int wave = tid >> 6, lane = tid & 63;

    // ---- params prologue: reduce this batch's 512 float4 partials ----
    {
        const float4* q = part + (size_t)b * 512;
        float4 a0 = q[tid], a1 = q[tid + 256];
        float4 acc;
        acc.x = a0.x + a1.x; acc.y = a0.y + a1.y;
        acc.z = a0.z + a1.z; acc.w = a0.w + a1.w;
        for (int off = 4; off < 64; off <<= 1) {
            acc.x += __shfl_down(acc.x, off);
            acc.y += __shfl_down(acc.y, off);
            acc.z += __shfl_down(acc.z, off);
            acc.w += __shfl_down(acc.w, off);
        }
        if (lane < 4) wsum[wave * 4 + lane] = acc;
        __syncthreads();
        if (tid < 4) {
            float4 t0 = wsum[0 * 4 + tid], t1 = wsum[1 * 4 + tid];
            float4 t2 = wsum[2 * 4 + tid], t3 = wsum[3 * 4 + tid];
            pooled[tid * 4 + 0] = (t0.x + t1.x + t2.x + t3.x) * (1.0f / 65536.0f);
            pooled[tid * 4 + 1] = (t0.y + t1.y + t2.y + t3.y) * (1.0f / 65536.0f);
            pooled[tid * 4 + 2] = (t0.z + t1.z + t2.z + t3.z) * (1.0f / 65536.0f);
            pooled[tid * 4 + 3] = (t0.w + t1.w + t2.w + t3.w) * (1.0f / 65536.0f);
        }
        __syncthreads();
        if (tid < 6) {
            float a = b_loc[tid];
#pragma unroll
            for (int c = 0; c < CC; ++c)
                a += pooled[c] * W_loc[c * 6 + tid];
            prs[tid] = a;
        }
        __syncthreads();
    }

    // Copy params to registers (LDS gets overwritten by staged rows).
    const float p0 = prs[0], p1 = prs[1], p2 = prs[2];
    const float p3 = prs[3], p4 = prs[4], p5 = prs[5];
    __syncthreads();

    const size_t base    = (size_t)b * NPIX;
    const int    local   = blk & 127;
    const int    h0      = local * 2;             // 2 output rows: h0, h0+1
    const int    pixBase = local * 512 + (tid >> 2);
    const int    cq      = tid & 3;

    // ---- needed input-row band from the tile's corner yc values ----
    const float yc00 = p0 * (float)h0       + p4;            // w = 0
    const float yc01 = p0 * (float)h0       + p1 * 255.f + p4;
    const float yc10 = p0 * (float)(h0 + 1) + p4;
    const float yc11 = p0 * (float)(h0 + 1) + p1 * 255.f + p4;
    const float ymn = fminf(fminf(yc00, yc01), fminf(yc10, yc11));
    const float ymx = fmaxf(fmaxf(yc00, yc01), fmaxf(yc10, yc11));
    const int y_lo = min(max((int)floorf(ymn), 0), HH - 1);
    const int y_hi = min(max((int)floorf(ymx) + 1, 0), HH - 1);
    const int NR   = y_hi - y_lo + 1;

    if (NR <= MAXR) {
        // ---- stage rows y_lo..y_hi (NR * 16 KB), coalesced ----
        const float4* src = x4 + (base + (size_t)y_lo * WW) * 4;
        const int nf4 = NR * 1024;                // 1024 float4 per row
        for (int i = tid; i < nf4; i += 256)
            ldsRows[i] = src[i];
        __syncthreads();

#pragma unroll 4
        for (int k = 0; k < 8; ++k) {
            const int pix = pixBase + k * 64;
            const int h = pix >> 8;
            const int w = pix & 255;

            const float fh = (float)h, fw = (float)w;
            const float yc = p0 * fh + p1 * fw + p4;
            const float xc = p2 * fh + p3 * fw + p5;

            const float y0f = floorf(yc), x0f = floorf(xc);
            const float wy = yc - y0f, wx = xc - x0f;
            const int y0 = (int)y0f, x0 = (int)x0f;
            const int s0  = min(max(y0, 0), HH - 1) - y_lo;       // LDS slot
            const int s1  = min(max(y0 + 1, 0), HH - 1) - y_lo;
            const int x0i = min(max(x0, 0), WW - 1);
            const int x1i = min(max(x0 + 1, 0), WW - 1);

            const float4 Ia = ldsRows[s0 * 1024 + x0i * 4 + cq];
            const float4 Ib = ldsRows[s0 * 1024 + x1i * 4 + cq];
            const float4 Ic = ldsRows[s1 * 1024 + x0i * 4 + cq];
            const float4 Id = ldsRows[s1 * 1024 + x1i * 4 + cq];

            const float wa = (1.f - wy) * (1.f - wx);
            const float wb = (1.f - wy) * wx;
            const float wc = wy * (1.f - wx);
            const float wd = wy * wx;

            float4 o;
            o.x = wa * Ia.x + wb * Ib.x + wc * Ic.x + wd * Id.x;
            o.y = wa * Ia.y + wb * Ib.y + wc * Ic.y + wd * Id.y;
            o.z = wa * Ia.z + wb * Ib.z + wc * Ic.z + wd * Id.z;
            o.w = wa * Ia.w + wb * Ib.w + wc * Ic.w + wd * Id.w;

            out[(base + pix) * 4 + cq] = o;
        }
    } else {
        // ---- fallback: direct global gather (round-6 path) ----
#pragma unroll 4
        for (int k = 0; k < 8; ++k) {
            const int pix = pixBase + k * 64;
            const int h = pix >> 8;
            const int w = pix & 255;

            const float fh = (float)h, fw = (float)w;
            const float yc = p0 * fh + p1 * fw + p4;
            const float xc = p2 * fh + p3 * fw + p5;

            const float y0f = floorf(yc), x0f = floorf(xc);
            const float wy = yc - y0f, wx = xc - x0f;
            const int y0 = (int)y0f, x0 = (int)x0f;
            const int y0i = min(max(y0, 0), HH - 1);
            const int y1i = min(max(y0 + 1, 0), HH - 1);
            const int x0i = min(max(x0, 0), WW - 1);
            const int x1i = min(max(x0 + 1, 0), WW - 1);

            const float4* r0 = x4 + (base + (size_t)y0i * WW) * 4 + cq;
            const float4* r1 = x4 + (base + (size_t)y1i * WW) * 4 + cq;
            const float4 Ia = r0[(size_t)x0i * 4];
            const float4 Ib = r0[(size_t)x1i * 4];
            const float4 Ic = r1[(size_t)x0i * 4];
            const float4 Id = r1[(size_t)x1i * 4];

            const float wa = (1.f - wy) * (1.f - wx);
            const float wb = (1.f - wy) * wx;
            const float wc = wy * (1.f - wx);
            const float wd = wy * wx;

            float4 o;
            o.x = wa * Ia.x + wb * Ib.x + wc * Ic.x + wd * Id.x;
            o.y = wa * Ia.y + wb * Ib.y + wc * Ic.y + wd * Id.y;
            o.z = wa * Ia.z + wb * Ib.z + wc * Ic.z + wd * Id.z;
            o.w = wa * Ia.w + wb * Ib.w + wc * Ic.w + wd * Id.w;

            out[(base + pix) * 4 + cq] = o;
        }
    }
}

extern "C" void kernel_launch(void* const* d_in, const int* in_sizes, int n_in,
                              void* d_out, int out_size, void* d_ws, size_t ws_size,
                              hipStream_t stream) {
    const float* x     = (const float*)d_in[0];   // (16,256,256,16) f32
    const float* W_loc = (const float*)d_in[1];   // (16,6) f32
    const float* b_loc = (const float*)d_in[2];   // (6,) f32
    // d_in[3] = coords_grid == np.indices((256,256)) -> recomputed on-chip.

    float4* part = (float4*)d_ws;                 // 2048*4 float4, fully written

    pool_partial<<<POOL_BLOCKS, 256, 0, stream>>>((const float4*)x, part);
    sample_fused<<<SAMPLE_BLOCKS, 256, MAXR * 16384, stream>>>(
        (const float4*)x, W_loc, b_loc, part, (float4*)d_out);
}